// Round 4
// baseline (373.925 us; speedup 1.0000x reference)
//
#include <hip/hip_runtime.h>
#include <hip/hip_bf16.h>
#include <cstdint>
#include <cstddef>

#define S_LEN 2048
#define D_HEAD 64
#define NBH 32                      // B*H = 2*16
#define NELEM 4194304               // NBH * S_LEN * D_HEAD
#define SUP 128                     // columns per store superblock

typedef __attribute__((ext_vector_type(8))) short short8;
typedef __attribute__((ext_vector_type(4))) float f32x4;

__device__ __forceinline__ short f2bf(float f) {
    union { float f; uint32_t u; } v; v.f = f;
    uint32_t u = v.u + 0x7FFFu + ((v.u >> 16) & 1u);   // RNE, inputs finite
    return (short)(u >> 16);
}

__device__ __forceinline__ uint32_t pkbf(float lo, float hi) {
    return ((uint32_t)(uint16_t)f2bf(hi) << 16) | (uint32_t)(uint16_t)f2bf(lo);
}

// K fp32 -> bf16, same layout
__global__ void convert_k_kernel(const float* __restrict__ K, short* __restrict__ Kb) {
    int i = blockIdx.x * 256 + threadIdx.x;
    float4 x = reinterpret_cast<const float4*>(K)[i];
    short4 y;
    y.x = f2bf(x.x); y.y = f2bf(x.y); y.z = f2bf(x.z); y.w = f2bf(x.w);
    reinterpret_cast<short4*>(Kb)[i] = y;
}

// V fp32 [bh][S][D] -> bf16 transposed [bh][D][S]
__global__ void transpose_v_kernel(const float* __restrict__ V, short* __restrict__ Vtb) {
    __shared__ float tile[64][65];
    const int bh = blockIdx.y;
    const int s0 = blockIdx.x * 64;
    const int d = threadIdx.x & 63;
    const int r = threadIdx.x >> 6;
    const float* vp = V + ((size_t)bh * S_LEN + s0) * D_HEAD;
    #pragma unroll
    for (int i = 0; i < 16; ++i) {
        int s = i * 4 + r;
        tile[s][d] = vp[(size_t)s * D_HEAD + d];
    }
    __syncthreads();
    short* op = Vtb + (size_t)bh * (D_HEAD * S_LEN) + s0;
    #pragma unroll
    for (int i = 0; i < 16; ++i) {
        int dd = i * 4 + r;
        op[(size_t)dd * S_LEN + d] = f2bf(tile[d][dd]);
    }
}

// One wave = 16 query rows. Swapped QK^T: mfma(A=K, B=Q) -> lane holds p for
// q = lane&15 at k = (lane>>4)*4 + reg (+16 per c1 tile).
// Pass 1: denominator + PV (unnormalized e; A-frag built by in-register
//         4x4 word transpose across lane-groups via 8 ds_bpermute).
// Pass 2: pure P stream: recompute scores, stage 128 cols in LDS, burst nt store.
__launch_bounds__(256, 4)
__global__ void attn_kernel(const float* __restrict__ Q,
                            const short* __restrict__ Kb,
                            const short* __restrict__ Vtb,
                            float* __restrict__ Out,
                            float* __restrict__ P) {
    __shared__ __align__(16) float stage[4][16][SUP];  // 32 KB: p f32 staging

    const int lane = threadIdx.x & 63;
    const int w    = threadIdx.x >> 6;
    const int bh   = blockIdx.y;
    const int qbase = blockIdx.x * 64 + w * 16;
    const int lrow = lane & 15;
    const int lgrp = lane >> 4;
    const float scale = 0.125f;                        // 1/sqrt(64)

    // Q fragment (B operand: col = lane&15 = q-row, d = lgrp*8+e)
    short8 q0, q1;
    {
        const float* qr = Q + ((size_t)bh * S_LEN + qbase + lrow) * D_HEAD + lgrp * 8;
        #pragma unroll
        for (int e = 0; e < 8; ++e) q0[e] = f2bf(qr[e]);
        #pragma unroll
        for (int e = 0; e < 8; ++e) q1[e] = f2bf(qr[e + 32]);
    }

    const short* Kp = Kb + (size_t)bh * (S_LEN * D_HEAD);
    const short* Vp = Vtb + (size_t)bh * (D_HEAD * S_LEN);

    // bpermute source lanes for the 4x4 word transpose (byte addr = lane*4)
    const int srcA = ((lane & 15) + ((lane >> 4) & 1) * 32) << 2;
    const int srcB = srcA + (16 << 2);
    const bool glow = (lgrp < 2);

    // ---- pass 1: softmax denominator + PV with unnormalized e ----
    float l = 0.f;
    f32x4 acc[4] = {};
    for (int j0 = 0; j0 < S_LEN; j0 += 32) {
        const short* kr0 = Kp + (size_t)(j0 + lrow) * D_HEAD + lgrp * 8;
        const short* kr1 = kr0 + 16 * D_HEAD;
        short8 k00 = *reinterpret_cast<const short8*>(kr0);
        short8 k01 = *reinterpret_cast<const short8*>(kr0 + 32);
        short8 k10 = *reinterpret_cast<const short8*>(kr1);
        short8 k11 = *reinterpret_cast<const short8*>(kr1 + 32);
        short8 bv0 = *reinterpret_cast<const short8*>(Vp + (size_t)(0 * 16 + lrow) * S_LEN + j0 + lgrp * 8);
        short8 bv1 = *reinterpret_cast<const short8*>(Vp + (size_t)(1 * 16 + lrow) * S_LEN + j0 + lgrp * 8);
        short8 bv2 = *reinterpret_cast<const short8*>(Vp + (size_t)(2 * 16 + lrow) * S_LEN + j0 + lgrp * 8);
        short8 bv3 = *reinterpret_cast<const short8*>(Vp + (size_t)(3 * 16 + lrow) * S_LEN + j0 + lgrp * 8);
        f32x4 c0 = {0.f, 0.f, 0.f, 0.f};
        f32x4 c1 = {0.f, 0.f, 0.f, 0.f};
        c0 = __builtin_amdgcn_mfma_f32_16x16x32_bf16(k00, q0, c0, 0, 0, 0);
        c0 = __builtin_amdgcn_mfma_f32_16x16x32_bf16(k01, q1, c0, 0, 0, 0);
        c1 = __builtin_amdgcn_mfma_f32_16x16x32_bf16(k10, q0, c1, 0, 0, 0);
        c1 = __builtin_amdgcn_mfma_f32_16x16x32_bf16(k11, q1, c1, 0, 0, 0);

        float e0[4], e1[4];
        #pragma unroll
        for (int rr = 0; rr < 4; ++rr) {
            e0[rr] = __expf(c0[rr] * scale);
            e1[rr] = __expf(c1[rr] * scale);
            l += e0[rr] + e1[rr];
        }
        // lane (q,g) holds global k-pair words m: w00=2g, w01=2g+1, w10=8+2g, w11=9+2g
        int w00 = (int)pkbf(e0[0], e0[1]);
        int w01 = (int)pkbf(e0[2], e0[3]);
        int w10 = (int)pkbf(e1[0], e1[1]);
        int w11 = (int)pkbf(e1[2], e1[3]);
        // A-frag for lane (q,g) needs words m = 4g..4g+3
        int t0 = __builtin_amdgcn_ds_bpermute(srcA, w00);
        int t1 = __builtin_amdgcn_ds_bpermute(srcA, w01);
        int t2 = __builtin_amdgcn_ds_bpermute(srcB, w00);
        int t3 = __builtin_amdgcn_ds_bpermute(srcB, w01);
        int u0 = __builtin_amdgcn_ds_bpermute(srcA, w10);
        int u1 = __builtin_amdgcn_ds_bpermute(srcA, w11);
        int u2 = __builtin_amdgcn_ds_bpermute(srcB, w10);
        int u3 = __builtin_amdgcn_ds_bpermute(srcB, w11);
        union { short8 s8; int wd[4]; } fr;
        fr.wd[0] = glow ? t0 : u0;
        fr.wd[1] = glow ? t1 : u1;
        fr.wd[2] = glow ? t2 : u2;
        fr.wd[3] = glow ? t3 : u3;

        acc[0] = __builtin_amdgcn_mfma_f32_16x16x32_bf16(fr.s8, bv0, acc[0], 0, 0, 0);
        acc[1] = __builtin_amdgcn_mfma_f32_16x16x32_bf16(fr.s8, bv1, acc[1], 0, 0, 0);
        acc[2] = __builtin_amdgcn_mfma_f32_16x16x32_bf16(fr.s8, bv2, acc[2], 0, 0, 0);
        acc[3] = __builtin_amdgcn_mfma_f32_16x16x32_bf16(fr.s8, bv3, acc[3], 0, 0, 0);
    }
    l += __shfl_xor(l, 16);
    l += __shfl_xor(l, 32);
    const float rl = 1.0f / l;                         // denominator for q = lrow

    // ---- pass 2: pure P stream (recompute scores, stage, burst nt store) ----
    char* stg = (char*)&stage[w][0][0];
    const int swz = (lrow & 7) << 4;
    float* Pb = P + (size_t)bh * S_LEN * S_LEN;

    for (int sup = 0; sup < S_LEN; sup += SUP) {
        #pragma unroll
        for (int jj = 0; jj < SUP / 32; ++jj) {
            const int j0 = sup + jj * 32;
            const short* kr0 = Kp + (size_t)(j0 + lrow) * D_HEAD + lgrp * 8;
            const short* kr1 = kr0 + 16 * D_HEAD;
            short8 k00 = *reinterpret_cast<const short8*>(kr0);
            short8 k01 = *reinterpret_cast<const short8*>(kr0 + 32);
            short8 k10 = *reinterpret_cast<const short8*>(kr1);
            short8 k11 = *reinterpret_cast<const short8*>(kr1 + 32);
            f32x4 c0 = {0.f, 0.f, 0.f, 0.f};
            f32x4 c1 = {0.f, 0.f, 0.f, 0.f};
            c0 = __builtin_amdgcn_mfma_f32_16x16x32_bf16(k00, q0, c0, 0, 0, 0);
            c0 = __builtin_amdgcn_mfma_f32_16x16x32_bf16(k01, q1, c0, 0, 0, 0);
            c1 = __builtin_amdgcn_mfma_f32_16x16x32_bf16(k10, q0, c1, 0, 0, 0);
            c1 = __builtin_amdgcn_mfma_f32_16x16x32_bf16(k11, q1, c1, 0, 0, 0);

            f32x4 p0, p1;
            #pragma unroll
            for (int rr = 0; rr < 4; ++rr) {
                p0[rr] = __expf(c0[rr] * scale) * rl;
                p1[rr] = __expf(c1[rr] * scale) * rl;
            }
            // stage normalized p (f32, swizzled): col = jj*32 + ct*16 + lgrp*4 + rr
            *(f32x4*)(stg + ((lrow * 512 + ((jj * 32 + lgrp * 4) << 2)) ^ swz)) = p0;
            *(f32x4*)(stg + ((lrow * 512 + ((jj * 32 + 16 + lgrp * 4) << 2)) ^ swz)) = p1;
        }

        // order all stage writes before cross-lane reads (once per 128 cols)
        asm volatile("s_waitcnt lgkmcnt(0)" ::: "memory");
        // burst store: 2 rows x 512B contiguous per instruction, nontemporal
        #pragma unroll
        for (int rb = 0; rb < 8; ++rb) {
            const int r = rb * 2 + (lane >> 5);
            const int c = lane & 31;
            f32x4 pv = *(const f32x4*)(stg + ((r * 512 + c * 16) ^ ((r & 7) << 4)));
            __builtin_nontemporal_store(pv,
                (f32x4*)(Pb + (size_t)(qbase + r) * S_LEN + sup + c * 4));
        }
        // ensure the cross-lane reads above completed before next sup overwrites
        asm volatile("s_waitcnt lgkmcnt(0)" ::: "memory");
    }

    // epilogue: Out[q = lgrp*4+rr][d = vt*16+lrow]; acc needs rl of q-row
    // lgrp*4+rr, but this lane's rl is for q-row lrow -> redistribute via shfl
    // (lanes 0..15 hold rl for q-rows 0..15).
    float rlo[4];
    #pragma unroll
    for (int rr = 0; rr < 4; ++rr) rlo[rr] = __shfl(rl, lgrp * 4 + rr);

    float* ob = Out + ((size_t)bh * S_LEN + qbase + lgrp * 4) * D_HEAD + lrow;
    #pragma unroll
    for (int vt = 0; vt < 4; ++vt) {
        #pragma unroll
        for (int rr = 0; rr < 4; ++rr) {
            ob[(size_t)rr * D_HEAD + vt * 16] = acc[vt][rr] * rlo[rr];
        }
    }
}

extern "C" void kernel_launch(void* const* d_in, const int* in_sizes, int n_in,
                              void* d_out, int out_size, void* d_ws, size_t ws_size,
                              hipStream_t stream) {
    const float* Q = (const float*)d_in[0];
    const float* K = (const float*)d_in[1];
    const float* V = (const float*)d_in[2];
    float* Out = (float*)d_out;
    float* P = Out + (size_t)NELEM;                    // outputs concatenated flat
    short* Kb = (short*)d_ws;                          // 8.4 MB
    short* Vtb = Kb + (size_t)NELEM;                   // 8.4 MB (needs ws >= 16.8 MB)

    convert_k_kernel<<<NELEM / (256 * 4), 256, 0, stream>>>(K, Kb);
    transpose_v_kernel<<<dim3(S_LEN / 64, NBH), 256, 0, stream>>>(V, Vtb);
    attn_kernel<<<dim3(S_LEN / 64, NBH), 256, 0, stream>>>(Q, Kb, Vtb, Out, P);
}